// Round 2
// baseline (272.984 us; speedup 1.0000x reference)
//
#include <hip/hip_runtime.h>
#include <math.h>

#define S 16    // states
#define C 8     // characters
#define B 64    // batch
#define L 4096  // sequence length
#define K 64    // chunks per batch
#define LC (L / K)  // steps per chunk = 64
#define PSTRIDE 17  // padded row stride for P in LDS (bank-conflict-free)

__device__ __forceinline__ float hsig(float x) {
    return x / (1.0f + fabsf(x)) * 0.5f + 0.5f;
}

// ws layout (floats):
//   [0, 2048)      : normalized transition probs T[p][c][n]
//   [2048, 2064)   : initial state probs (16)
//   [2064, 2080)   : accepting state logprobs (16)
//   [2304, 2304 + B*K*256)           : per-chunk stochastic 16x16 products
//   [2304 + B*K*256, + B*K)          : per-chunk sum of log X_l

__global__ void prep_kernel(const float* __restrict__ invh_init,
                            const float* __restrict__ invh_T,
                            const float* __restrict__ invh_acc,
                            float* __restrict__ ws) {
    int t = threadIdx.x;  // 128 threads
    if (t < S * C) {
        float v[S];
        float s = 0.0f;
#pragma unroll
        for (int n = 0; n < S; n++) {
            v[n] = hsig(invh_T[t * S + n]);
            s += v[n];
        }
        float inv = 1.0f / s;
#pragma unroll
        for (int n = 0; n < S; n++) ws[t * S + n] = v[n] * inv;
    }
    __shared__ float si[S];
    if (t < S) si[t] = hsig(invh_init[t]);
    __syncthreads();
    if (t < S) {
        float s = 0.0f;
#pragma unroll
        for (int n = 0; n < S; n++) s += si[n];
        ws[2048 + t] = si[t] / s;
        ws[2064 + t] = logf(hsig(invh_acc[t]));
    }
}

// One block per (chunk, batch). Computes the row-stochastic product
// P = S_{l0} @ ... @ S_{l0+LC-1} where S_l[p][n] = sum_c T[p][c][n]*xn[l][c],
// xn[l][c] = exp(logx - logX_l), logX_l = logsumexp_c logx[b][l][c].
// Also writes sum_l logX_l for the chunk.
__global__ void __launch_bounds__(256) chunk_kernel(const float* __restrict__ logx,
                                                    const float* __restrict__ ws,
                                                    float* __restrict__ chunkP,
                                                    float* __restrict__ chunkLog) {
    int t = threadIdx.x;       // 256 threads: t = p*16 + n
    int chunk = blockIdx.x;    // K
    int b = blockIdx.y;        // B
    int p = t >> 4, n = t & 15;

    __shared__ float Tl[C * 256];          // [c][p*16+n] = T[p][c][n]
    __shared__ float xs[LC * C];           // logx tile -> normalized x tile
    __shared__ float lX[LC];               // per-step logX
    __shared__ float Pl[2][S * PSTRIDE];   // double-buffered running product (padded)
    __shared__ float Ml[256];              // current step matrix

#pragma unroll
    for (int c = 0; c < C; c++) Tl[c * 256 + t] = ws[p * (C * S) + c * S + n];

    const float* xg = logx + ((size_t)b * L + (size_t)chunk * LC) * C;
    xs[t] = xg[t];
    xs[t + 256] = xg[t + 256];

    if (t < S * PSTRIDE - 256) Pl[0][256 + t] = 0.0f;  // tail init (pad region)
    __syncthreads();

    // Normalize each step's x: thread l (l < 64) handles its 8 chars.
    if (t < LC) {
        float m = -INFINITY;
#pragma unroll
        for (int c = 0; c < C; c++) m = fmaxf(m, xs[t * C + c]);
        float ssum = 0.0f;
#pragma unroll
        for (int c = 0; c < C; c++) ssum += __expf(xs[t * C + c] - m);
        float lx = m + __logf(ssum);
        lX[t] = lx;
#pragma unroll
        for (int c = 0; c < C; c++) xs[t * C + c] = __expf(xs[t * C + c] - lx);
    }
    // P = identity (padded layout)
    Pl[0][p * PSTRIDE + n] = (p == n) ? 1.0f : 0.0f;
    __syncthreads();

    int cur = 0;
    for (int l = 0; l < LC; l++) {
        // M[p][n] = sum_c T[p][c][n] * xn[l][c]
        float m = 0.0f;
#pragma unroll
        for (int c = 0; c < C; c++) m += Tl[c * 256 + t] * xs[l * C + c];
        Ml[t] = m;
        __syncthreads();
        // P_new[p][n] = sum_k P[p][k] * M[k][n]
        float acc = 0.0f;
#pragma unroll
        for (int k = 0; k < S; k++) acc += Pl[cur][p * PSTRIDE + k] * Ml[k * 16 + n];
        Pl[1 - cur][p * PSTRIDE + n] = acc;
        cur ^= 1;
        __syncthreads();
    }

    chunkP[((size_t)b * K + chunk) * 256 + t] = Pl[cur][p * PSTRIDE + n];
    if (t == 0) {
        float s = 0.0f;
#pragma unroll
        for (int l = 0; l < LC; l++) s += lX[l];
        chunkLog[b * K + chunk] = s;
    }
}

// One block per batch: fold chunk products into init vector (stays a prob
// vector), accumulate log-scale, then the final accepting logsumexp.
__global__ void combine_kernel(const float* __restrict__ ws,
                               const float* __restrict__ chunkP,
                               const float* __restrict__ chunkLog,
                               float* __restrict__ out) {
    int b = blockIdx.x;
    int t = threadIdx.x;  // 64 threads
    __shared__ float vl[S];
    __shared__ float nv[S];
    if (t < S) vl[t] = ws[2048 + t];
    __syncthreads();
    for (int k = 0; k < K; k++) {
        const float* P = chunkP + ((size_t)b * K + k) * 256;
        if (t < S) {
            float a = 0.0f;
#pragma unroll
            for (int p = 0; p < S; p++) a += vl[p] * P[p * 16 + t];
            nv[t] = a;
        }
        __syncthreads();
        if (t < S) vl[t] = nv[t];
        __syncthreads();
    }
    if (t == 0) {
        double total = 0.0;
        for (int k = 0; k < K; k++) total += (double)chunkLog[b * K + k];
        float sarr[S];
        float amax = -INFINITY;
#pragma unroll
        for (int n = 0; n < S; n++) {
            float v = logf(vl[n] + 1e-30f) + ws[2064 + n];  // + total later
            sarr[n] = v;
            amax = fmaxf(amax, v);
        }
        float a2 = isfinite(amax) ? amax : 0.0f;
        float sum = 0.0f;
#pragma unroll
        for (int n = 0; n < S; n++) sum += expf(sarr[n] - a2);
        out[b] = (float)((double)logf(sum) + (double)a2 + total);
    }
}

extern "C" void kernel_launch(void* const* d_in, const int* in_sizes, int n_in,
                              void* d_out, int out_size, void* d_ws, size_t ws_size,
                              hipStream_t stream) {
    const float* logx = (const float*)d_in[0];   // (B, L, C) f32
    const float* init = (const float*)d_in[1];   // (S,) f32
    const float* T    = (const float*)d_in[2];   // (S, C, S) f32
    const float* acc  = (const float*)d_in[3];   // (S,) f32
    float* ws  = (float*)d_ws;
    float* out = (float*)d_out;
    float* chunkP   = ws + 2304;
    float* chunkLog = chunkP + (size_t)B * K * 256;

    prep_kernel<<<1, 128, 0, stream>>>(init, T, acc, ws);
    chunk_kernel<<<dim3(K, B), 256, 0, stream>>>(logx, ws, chunkP, chunkLog);
    combine_kernel<<<B, 64, 0, stream>>>(ws, chunkP, chunkLog, out);
}

// Round 3
// 104.709 us; speedup vs baseline: 2.6071x; 2.6071x over previous
//
#include <hip/hip_runtime.h>
#include <math.h>

#define S 16
#define C 8
#define NB 64   // batch
#define L 4096
#define K 64    // chunks per batch
#define LC 64   // steps per chunk

typedef __attribute__((ext_vector_type(8))) short bf16x8;
typedef __attribute__((ext_vector_type(4))) float f32x4;

// ws byte layout:
//  0      : TmT bf16 [256][32]   (16 KB)  Tnorm[p][c][n] at [(p*16+n)*32 + c], c in [8,32) zero
//  16384  : initp  f32[16]
//  16448  : acclog f32[16]
//  16512  : chunkLog f32[4096]   (16 KB)
//  33280  : chunkP bf16 [4096][256] (2 MB) ; chunk even -> row-major, odd -> transposed
#define WS_TMT  0
#define WS_INIT 16384
#define WS_ACC  16448
#define WS_CLOG 16512
#define WS_CP   33280

__device__ __forceinline__ float hsig(float x) {
    return x / (1.0f + fabsf(x)) * 0.5f + 0.5f;
}
__device__ __forceinline__ unsigned short f2bf(float f) {
    unsigned int u = __float_as_uint(f);
    return (unsigned short)((u + 0x7fffu + ((u >> 16) & 1u)) >> 16);
}

// One 16x16 product D = Lmat * Rmat via mfma_f32_16x16x32_bf16 (K zero-padded to 32).
// lA: left matrix, row-major [m][k] bf16. rT: right matrix TRANSPOSED [n][k] bf16.
__device__ __forceinline__ f32x4 prod16(const unsigned short* lA, const unsigned short* rT, int lane) {
    int col = lane & 15, quad = lane >> 4;
    bf16x8 a = {0, 0, 0, 0, 0, 0, 0, 0};
    bf16x8 b = {0, 0, 0, 0, 0, 0, 0, 0};
    if (quad < 2) {  // k = quad*8 + j in [0,16) real, quads 2,3 are the K-pad
        a = *(const bf16x8*)(lA + col * 16 + quad * 8);
        b = *(const bf16x8*)(rT + col * 16 + quad * 8);
    }
    f32x4 c = {0.f, 0.f, 0.f, 0.f};
    return __builtin_amdgcn_mfma_f32_16x16x32_bf16(a, b, c, 0, 0, 0);
}

// Store D-frag (row = quad*4+r, col = lane&15) to LDS as bf16.
// transposed=true -> [col][row] (contiguous b64 per lane); else row-major scatter.
__device__ __forceinline__ void store16_lds(unsigned short* dst, f32x4 d, int lane, bool transposed) {
    int col = lane & 15, quad = lane >> 4;
    if (transposed) {
        unsigned long long pk = (unsigned long long)f2bf(d[0])
                              | ((unsigned long long)f2bf(d[1]) << 16)
                              | ((unsigned long long)f2bf(d[2]) << 32)
                              | ((unsigned long long)f2bf(d[3]) << 48);
        *(unsigned long long*)(dst + col * 16 + quad * 4) = pk;
    } else {
#pragma unroll
        for (int r = 0; r < 4; r++) dst[(quad * 4 + r) * 16 + col] = f2bf(d[r]);
    }
}

// Balanced-tree product of 64 matrices in bufA (slot i: even -> row-major, odd -> transposed).
// Returns the root D-frag (valid in wave 0). 4 waves; own-quarter slot discipline keeps
// lv1..lv4 barrier-free (within-wave LDS deps only).
__device__ __forceinline__ f32x4 tree64(unsigned short* bufA, unsigned short* bufB, int tid) {
    int lane = tid & 63, w = tid >> 6;
    // lv1: 32 products; wave w -> i = 8w+i2; out bufB[i]
#pragma unroll
    for (int i2 = 0; i2 < 8; i2++) {
        int i = 8 * w + i2;
        f32x4 d = prod16(bufA + (size_t)(16 * w + 2 * i2) * 256,
                         bufA + (size_t)(16 * w + 2 * i2 + 1) * 256, lane);
        store16_lds(bufB + (size_t)i * 256, d, lane, (i & 1) != 0);
    }
    // lv2: 16 products; i = 4w+i2; reads bufB[2i],[2i+1] (own); out bufA[16w+8+i2]
#pragma unroll
    for (int i2 = 0; i2 < 4; i2++) {
        int i = 4 * w + i2;
        f32x4 d = prod16(bufB + (size_t)(2 * i) * 256, bufB + (size_t)(2 * i + 1) * 256, lane);
        store16_lds(bufA + (size_t)(16 * w + 8 + i2) * 256, d, lane, (i & 1) != 0);
    }
    // lv3: 8 products; i = 2w+i2; lv2 slot(j) = 16*(j>>2)+8+(j&3); out bufB[8w+i2]
#pragma unroll
    for (int i2 = 0; i2 < 2; i2++) {
        int i = 2 * w + i2;
        int jl = 2 * i, jr = 2 * i + 1;
        f32x4 d = prod16(bufA + (size_t)(16 * (jl >> 2) + 8 + (jl & 3)) * 256,
                         bufA + (size_t)(16 * (jr >> 2) + 8 + (jr & 3)) * 256, lane);
        store16_lds(bufB + (size_t)(8 * w + i2) * 256, d, lane, (i & 1) != 0);
    }
    // lv4: 4 products; i = w; reads bufB[8w],[8w+1]; out bufA[16w], parity w
    {
        f32x4 d = prod16(bufB + (size_t)(8 * w) * 256, bufB + (size_t)(8 * w + 1) * 256, lane);
        store16_lds(bufA + (size_t)(16 * w) * 256, d, lane, (w & 1) != 0);
    }
    __syncthreads();
    // lv5: wave0: bufA[0]*bufA[16] -> bufB[0] (row-major); wave1: bufA[32]*bufA[48] -> bufB[1] (transposed)
    if (w < 2) {
        f32x4 d = prod16(bufA + (size_t)(32 * w) * 256, bufA + (size_t)(32 * w + 16) * 256, lane);
        store16_lds(bufB + (size_t)w * 256, d, lane, w != 0);
    }
    __syncthreads();
    // lv6 (all waves compute; wave0's value is used)
    return prod16(bufB, bufB + 256, lane);
}

__global__ void prep_kernel(const float* __restrict__ invh_init,
                            const float* __restrict__ invh_T,
                            const float* __restrict__ invh_acc,
                            unsigned char* __restrict__ wsb) {
    int t = threadIdx.x;  // 256
    uint4* tz = (uint4*)(wsb + WS_TMT);
    uint4 z4 = {0u, 0u, 0u, 0u};
#pragma unroll
    for (int j = 0; j < 4; j++) tz[t + 256 * j] = z4;
    __syncthreads();
    if (t < S * C) {
        int p = t >> 3, c = t & 7;
        float v[S]; float s = 0.f;
#pragma unroll
        for (int n = 0; n < S; n++) { v[n] = hsig(invh_T[t * S + n]); s += v[n]; }
        float inv = 1.f / s;
        unsigned short* TmT = (unsigned short*)(wsb + WS_TMT);
#pragma unroll
        for (int n = 0; n < S; n++) TmT[(p * 16 + n) * 32 + c] = f2bf(v[n] * inv);
    }
    __shared__ float si[S];
    if (t < S) si[t] = hsig(invh_init[t]);
    __syncthreads();
    if (t < S) {
        float s = 0.f;
#pragma unroll
        for (int n = 0; n < S; n++) s += si[n];
        ((float*)(wsb + WS_INIT))[t] = si[t] / s;
        ((float*)(wsb + WS_ACC))[t] = logf(hsig(invh_acc[t]));
    }
}

__global__ void __launch_bounds__(256) chunk_kernel(const float* __restrict__ logx,
                                                    unsigned char* __restrict__ wsb) {
    __shared__ __align__(16) unsigned short bufA[64 * 256];  // 32 KB
    __shared__ __align__(16) unsigned short bufB[32 * 256];  // 16 KB
    __shared__ __align__(16) unsigned short xsbf[LC * 8];    // 1 KB
    __shared__ float lXs[LC];

    int tid = threadIdx.x, lane = tid & 63, w = tid >> 6;
    int chunk = blockIdx.x, b = blockIdx.y;
    int col = lane & 15, quad = lane >> 4;

    // Preload construct B-frags (wave w owns p-tiles 4w..4w+3). Chunk-invariant.
    const unsigned short* TmT = (const unsigned short*)(wsb + WS_TMT);
    bf16x8 btile[4];
#pragma unroll
    for (int jj = 0; jj < 4; jj++) {
        int pn = (4 * w + jj) * 16 + col;
        btile[jj] = *(const bf16x8*)(TmT + pn * 32 + quad * 8);
    }

    // Stage logx tile (512 f32) into bufB scratch.
    float* stage = (float*)bufB;
    const float* xg = logx + ((size_t)b * L + (size_t)chunk * LC) * C;
    stage[tid] = xg[tid];
    stage[tid + 256] = xg[tid + 256];
    __syncthreads();

    // Per-step logsumexp normalize: xn = exp(logx - lX), row-stochastic scaling.
    if (tid < LC) {
        float v[C]; float m = -INFINITY;
#pragma unroll
        for (int c = 0; c < C; c++) { v[c] = stage[tid * C + c]; m = fmaxf(m, v[c]); }
        float s = 0.f;
#pragma unroll
        for (int c = 0; c < C; c++) { v[c] = __expf(v[c] - m); s += v[c]; }
        lXs[tid] = m + __logf(s);
        float inv = 1.0f / s;
        unsigned int* xrow = (unsigned int*)(xsbf + tid * C);
#pragma unroll
        for (int c = 0; c < 4; c++) {
            unsigned int lo = f2bf(v[2 * c] * inv);
            unsigned int hi = f2bf(v[2 * c + 1] * inv);
            xrow[c] = lo | (hi << 16);
        }
    }
    __syncthreads();

    // Construct 64 step-matrices M_l = X * Tm via MFMA; D rows are steps l.
    // Write M_l to bufA[l]: l even -> row-major, odd -> transposed.
#pragma unroll
    for (int lt = 0; lt < 4; lt++) {
        bf16x8 af = {0, 0, 0, 0, 0, 0, 0, 0};
        if (quad == 0) af = *(const bf16x8*)(xsbf + (lt * 16 + col) * C);  // k=c<8 real
#pragma unroll
        for (int jj = 0; jj < 4; jj++) {
            f32x4 c0 = {0.f, 0.f, 0.f, 0.f};
            f32x4 d = __builtin_amdgcn_mfma_f32_16x16x32_bf16(af, btile[jj], c0, 0, 0, 0);
            int p = 4 * w + jj;
#pragma unroll
            for (int r = 0; r < 4; r++) {
                int l = lt * 16 + quad * 4 + r;
                unsigned short v = f2bf(d[r]);
                int idx = (l & 1) ? (col * 16 + p) : (p * 16 + col);
                bufA[(size_t)l * 256 + idx] = v;
            }
        }
    }
    __syncthreads();

    f32x4 root = tree64(bufA, bufB, tid);

    unsigned short* cp = (unsigned short*)(wsb + WS_CP) + ((size_t)b * K + chunk) * 256;
    if (w == 0) {
        if (chunk & 1) {
            unsigned long long pk = (unsigned long long)f2bf(root[0])
                                  | ((unsigned long long)f2bf(root[1]) << 16)
                                  | ((unsigned long long)f2bf(root[2]) << 32)
                                  | ((unsigned long long)f2bf(root[3]) << 48);
            *(unsigned long long*)(cp + col * 16 + quad * 4) = pk;
        } else {
#pragma unroll
            for (int r = 0; r < 4; r++) cp[(quad * 4 + r) * 16 + col] = f2bf(root[r]);
        }
    } else if (w == 1) {
        float myl = lXs[lane];
#pragma unroll
        for (int d = 1; d < 64; d <<= 1) myl += __shfl_xor(myl, d);
        if (lane == 0) ((float*)(wsb + WS_CLOG))[b * K + chunk] = myl;
    }
}

__global__ void __launch_bounds__(256) reduce_kernel(unsigned char* __restrict__ wsb,
                                                     float* __restrict__ out) {
    __shared__ __align__(16) unsigned short bufA[64 * 256];
    __shared__ __align__(16) unsigned short bufB[32 * 256];
    int tid = threadIdx.x, lane = tid & 63, w = tid >> 6;
    int b = blockIdx.x;

    const uint4* src = (const uint4*)((const unsigned short*)(wsb + WS_CP) + (size_t)b * K * 256);
    uint4* dst = (uint4*)bufA;
#pragma unroll
    for (int j = 0; j < 8; j++) dst[tid + 256 * j] = src[tid + 256 * j];
    __syncthreads();

    f32x4 root = tree64(bufA, bufB, tid);

    if (w == 0) {
        int col = lane & 15, quad = lane >> 4;
        const float* initp = (const float*)(wsb + WS_INIT);
        const float* acclog = (const float*)(wsb + WS_ACC);
        float part = 0.f;
#pragma unroll
        for (int r = 0; r < 4; r++) part += initp[quad * 4 + r] * root[r];
        part += __shfl_xor(part, 16);
        part += __shfl_xor(part, 32);
        float lp = logf(part + 1e-30f) + acclog[col];
        float mx = lp;
#pragma unroll
        for (int d = 1; d < 16; d <<= 1) mx = fmaxf(mx, __shfl_xor(mx, d));
        float a2 = isfinite(mx) ? mx : 0.0f;  // jax.nn.logsumexp semantics
        float sm = expf(lp - a2);
#pragma unroll
        for (int d = 1; d < 16; d <<= 1) sm += __shfl_xor(sm, d);
        const float* clog = (const float*)(wsb + WS_CLOG);
        float cl = clog[b * K + lane];
#pragma unroll
        for (int d = 1; d < 64; d <<= 1) cl += __shfl_xor(cl, d);
        if (lane == 0) out[b] = logf(sm) + a2 + cl;
    }
}

extern "C" void kernel_launch(void* const* d_in, const int* in_sizes, int n_in,
                              void* d_out, int out_size, void* d_ws, size_t ws_size,
                              hipStream_t stream) {
    const float* logx = (const float*)d_in[0];   // (B, L, C) f32
    const float* init = (const float*)d_in[1];   // (S,) f32
    const float* T    = (const float*)d_in[2];   // (S, C, S) f32
    const float* acc  = (const float*)d_in[3];   // (S,) f32
    unsigned char* wsb = (unsigned char*)d_ws;
    float* out = (float*)d_out;

    prep_kernel<<<1, 256, 0, stream>>>(init, T, acc, wsb);
    chunk_kernel<<<dim3(K, NB), 256, 0, stream>>>(logx, wsb);
    reduce_kernel<<<NB, 256, 0, stream>>>(wsb, out);
}

// Round 5
// 93.546 us; speedup vs baseline: 2.9182x; 1.1193x over previous
//
#include <hip/hip_runtime.h>
#include <math.h>

#define S 16
#define C 8
#define NB 64   // batch
#define L 4096
#define K 64    // chunks per batch
#define LC 64   // steps per chunk

#define SLOT 324  // bf16 elems per matrix slot = 648 B (162 banks % 32 == 2 -> quad-distinct slot bases)
#define RS 20     // row stride in elems (40 B -> conflict-free row-major scatters)

typedef __attribute__((ext_vector_type(8))) short bf16x8;
typedef __attribute__((ext_vector_type(4))) short bf16x4;
typedef __attribute__((ext_vector_type(4))) float f32x4;
typedef unsigned long long ull;

// ws byte layout:
#define WS_TN   0         // f32 Tnorm[p][c][n] = [16][8][16]  (8 KB)
#define WS_INIT 8192      // f32[16]
#define WS_ACC  8256      // f32[16]
#define WS_CLOG 8320      // f32[4096]  (16 KB)
#define WS_TTT  24704     // bf16 TTT[flat=(p*16+n)][cc'=64]  (32 KB), B-frag-ready
#define WS_CP   57472     // bf16 chunkP[4096][256]; even chunk row-major, odd [col][row]

__device__ __forceinline__ float hsig(float x) {
    return x / (1.0f + fabsf(x)) * 0.5f + 0.5f;
}
__device__ __forceinline__ unsigned short f2bf(float f) {
    unsigned int u = __float_as_uint(f);
    return (unsigned short)((u + 0x7fffu + ((u >> 16) & 1u)) >> 16);
}

// Load an MFMA operand frag from a padded slot. Both layouts put the
// contraction index contiguous: lane reads 8 bf16 at i1*RS + quad*8.
__device__ __forceinline__ bf16x8 ldfrag(const unsigned short* base, int lane) {
    int col = lane & 15, quad = lane >> 4;
    bf16x8 f = {0, 0, 0, 0, 0, 0, 0, 0};
    if (quad < 2) {  // quads 2,3 are the K-pad (16 -> 32)
        const bf16x4* p = (const bf16x4*)(base + col * RS + quad * 8);
        bf16x4 lo = p[0], hi = p[1];
        f[0] = lo[0]; f[1] = lo[1]; f[2] = lo[2]; f[3] = lo[3];
        f[4] = hi[0]; f[5] = hi[1]; f[6] = hi[2]; f[7] = hi[3];
    }
    return f;
}

// D = slots[sa] * slots[sb]; sa must be row-major (even-parity), sb transposed (odd).
__device__ __forceinline__ f32x4 prod2(const unsigned short* slots, int sa, int sb, int lane) {
    bf16x8 a = ldfrag(slots + sa * SLOT, lane);
    bf16x8 b = ldfrag(slots + sb * SLOT, lane);
    f32x4 c = {0.f, 0.f, 0.f, 0.f};
    return __builtin_amdgcn_mfma_f32_16x16x32_bf16(a, b, c, 0, 0, 0);
}

// Store D-frag (row=quad*4+r, col=lane&15) into a padded slot.
// odd -> [col][row] stride RS (packed b64); even -> row-major stride RS.
__device__ __forceinline__ void store16(unsigned short* slot, f32x4 d, int lane, bool odd) {
    int col = lane & 15, quad = lane >> 4;
    if (odd) {
        ull pk = (ull)f2bf(d[0]) | ((ull)f2bf(d[1]) << 16)
               | ((ull)f2bf(d[2]) << 32) | ((ull)f2bf(d[3]) << 48);
        *(ull*)(slot + col * RS + quad * 4) = pk;
    } else {
#pragma unroll
        for (int r = 0; r < 4; r++) slot[(quad * 4 + r) * RS + col] = f2bf(d[r]);
    }
}

__global__ void prep_kernel(const float* __restrict__ invh_init,
                            const float* __restrict__ invh_T,
                            const float* __restrict__ invh_acc,
                            unsigned char* __restrict__ wsb) {
    int t = threadIdx.x;  // 128
    if (t < S * C) {
        float v[S]; float s = 0.f;
#pragma unroll
        for (int n = 0; n < S; n++) { v[n] = hsig(invh_T[t * S + n]); s += v[n]; }
        float inv = 1.f / s;
        float* Tn = (float*)(wsb + WS_TN);
#pragma unroll
        for (int n = 0; n < S; n++) Tn[t * S + n] = v[n] * inv;  // [p][c][n]
    }
    __shared__ float si[S];
    if (t < S) si[t] = hsig(invh_init[t]);
    __syncthreads();
    if (t < S) {
        float s = 0.f;
#pragma unroll
        for (int n = 0; n < S; n++) s += si[n];
        ((float*)(wsb + WS_INIT))[t] = si[t] / s;
        ((float*)(wsb + WS_ACC))[t] = logf(hsig(invh_acc[t]));
    }
}

// TT[c][c'] = T_c * T_{c'}; written B-frag-ready: TTT[(p*16+n)*64 + c*8+c'].
__global__ void prep2_kernel(unsigned char* __restrict__ wsb) {
    __shared__ float Tn[2048];
    int tid = threadIdx.x;  // 256
    const float* g = (const float*)(wsb + WS_TN);
#pragma unroll
    for (int j = 0; j < 8; j++) Tn[tid + 256 * j] = g[tid + 256 * j];
    __syncthreads();
    int cc = blockIdx.x, c = cc >> 3, cp = cc & 7;
    int p = tid >> 4, n = tid & 15;
    float acc = 0.f;
#pragma unroll
    for (int k = 0; k < S; k++) acc += Tn[p * 128 + c * 16 + k] * Tn[k * 128 + cp * 16 + n];
    ((unsigned short*)(wsb + WS_TTT))[tid * 64 + cc] = f2bf(acc);
}

__global__ void __launch_bounds__(256) chunk_kernel(const float* __restrict__ logx,
                                                    unsigned char* __restrict__ wsb) {
    // 62 slots: 0..31 pair-products Q_i; 32..47 lv1; 48..55 lv2; 56..59 lv3; 60..61 lv4.
    __shared__ __align__(16) unsigned short slots[62 * SLOT];  // 40176 B
    float* xs = (float*)(slots + 32 * SLOT);  // overlay (dead before lv1 writes)

    int tid = threadIdx.x, lane = tid & 63, w = tid >> 6;
    int col = lane & 15, quad = lane >> 4;
    int chunk = blockIdx.x, b = blockIdx.y;

    // Construct B-frags from global TTT (L2/L3-hot). Wave w owns p-tiles t=4w..4w+3.
    const unsigned short* TTT = (const unsigned short*)(wsb + WS_TTT);
    bf16x8 bfr[4][2];
#pragma unroll
    for (int jj = 0; jj < 4; jj++) {
        int t = 4 * w + jj;
#pragma unroll
        for (int kk = 0; kk < 2; kk++)
            bfr[jj][kk] = *(const bf16x8*)(TTT + (t * 16 + col) * 64 + kk * 32 + quad * 8);
    }

    // Stage logx tile (512 f32, coalesced).
    const float* xg = logx + ((size_t)b * L + (size_t)chunk * LC) * C;
    xs[tid] = xg[tid];
    xs[tid + 256] = xg[tid + 256];
    __syncthreads();

    // Per-step logsumexp normalize (wave 0); chunkLog written here too.
    if (tid < LC) {
        float v[C]; float m = -INFINITY;
#pragma unroll
        for (int c = 0; c < C; c++) { v[c] = xs[tid * C + c]; m = fmaxf(m, v[c]); }
        float s = 0.f;
#pragma unroll
        for (int c = 0; c < C; c++) { v[c] = __expf(v[c] - m); s += v[c]; }
        float lx = m + __logf(s);
        float inv = 1.0f / s;
#pragma unroll
        for (int c = 0; c < C; c++) xs[tid * C + c] = v[c] * inv;
        float cl = lx;
#pragma unroll
        for (int d = 1; d < 64; d <<= 1) cl += __shfl_xor(cl, d);
        if (lane == 0) ((float*)(wsb + WS_CLOG))[b * K + chunk] = cl;
    }
    __syncthreads();

    // Construct A-frags: y[i][cc'] = xn[2i][c] * xn[2i+1][c'], i = mt*16+col,
    // k = kk*32+quad*8+j -> c = kk*4+quad, c' = j.
    bf16x8 afr[2][2];
#pragma unroll
    for (int mt = 0; mt < 2; mt++) {
        int i2 = 2 * (mt * 16 + col);  // = 2i
        const float4* x1p = (const float4*)(xs + (i2 + 1) * 8);
        float4 xa = x1p[0], xb = x1p[1];
#pragma unroll
        for (int kk = 0; kk < 2; kk++) {
            float x0 = xs[i2 * 8 + kk * 4 + quad];
            bf16x8 a;
            a[0] = (short)f2bf(x0 * xa.x); a[1] = (short)f2bf(x0 * xa.y);
            a[2] = (short)f2bf(x0 * xa.z); a[3] = (short)f2bf(x0 * xa.w);
            a[4] = (short)f2bf(x0 * xb.x); a[5] = (short)f2bf(x0 * xb.y);
            a[6] = (short)f2bf(x0 * xb.z); a[7] = (short)f2bf(x0 * xb.w);
            afr[mt][kk] = a;
        }
    }

    // Pair-product construct: Q_i (32 matrices) -> slots 0..31, parity i&1.
#pragma unroll
    for (int mt = 0; mt < 2; mt++)
#pragma unroll
        for (int jj = 0; jj < 4; jj++) {
            f32x4 acc = {0.f, 0.f, 0.f, 0.f};
#pragma unroll
            for (int kk = 0; kk < 2; kk++)
                acc = __builtin_amdgcn_mfma_f32_16x16x32_bf16(afr[mt][kk], bfr[jj][kk], acc, 0, 0, 0);
            int t = 4 * w + jj;  // = p
#pragma unroll
            for (int r = 0; r < 4; r++) {
                int i = mt * 16 + quad * 4 + r;
                int off = (i & 1) ? (col * RS + t) : (t * RS + col);
                slots[i * SLOT + off] = f2bf(acc[r]);
            }
        }
    __syncthreads();

    // Tree over 32 (lv1..lv3 barrier-free via wave ownership).
#pragma unroll
    for (int i2 = 0; i2 < 4; i2++) {
        int i = 4 * w + i2;
        store16(slots + (32 + i) * SLOT, prod2(slots, 2 * i, 2 * i + 1, lane), lane, i & 1);
    }
#pragma unroll
    for (int i2 = 0; i2 < 2; i2++) {
        int i = 2 * w + i2;
        store16(slots + (48 + i) * SLOT, prod2(slots, 32 + 2 * i, 32 + 2 * i + 1, lane), lane, i & 1);
    }
    store16(slots + (56 + w) * SLOT, prod2(slots, 48 + 2 * w, 48 + 2 * w + 1, lane), lane, w & 1);
    __syncthreads();
    if (w < 2)
        store16(slots + (60 + w) * SLOT, prod2(slots, 56 + 2 * w, 56 + 2 * w + 1, lane), lane, w & 1);
    __syncthreads();
    f32x4 root = prod2(slots, 60, 61, lane);

    if (w == 0) {
        unsigned short* cp = (unsigned short*)(wsb + WS_CP) + ((size_t)b * K + chunk) * 256;
        if (chunk & 1) {
            ull pk = (ull)f2bf(root[0]) | ((ull)f2bf(root[1]) << 16)
                   | ((ull)f2bf(root[2]) << 32) | ((ull)f2bf(root[3]) << 48);
            *(ull*)(cp + col * 16 + quad * 4) = pk;
        } else {
#pragma unroll
            for (int r = 0; r < 4; r++) cp[(quad * 4 + r) * 16 + col] = f2bf(root[r]);
        }
    }
}

__global__ void __launch_bounds__(256) reduce_kernel(unsigned char* __restrict__ wsb,
                                                     float* __restrict__ out) {
    // 126 slots: 0..63 in; 64..95 lv1; 96..111 lv2; 112..119 lv3; 120..123 lv4; 124..125 lv5.
    __shared__ __align__(16) unsigned short slots[126 * SLOT];  // ~79.7 KB
    int tid = threadIdx.x, lane = tid & 63, w = tid >> 6;
    int col = lane & 15, quad = lane >> 4;
    int b = blockIdx.x;

    // Copy 64 packed matrices into padded slots. One matrix = 256 elems = 32 uint4,
    // so slot = j>>5, u = j&31 (R4 bug: j>>4/&15 copied only half the data).
    const uint4* src = (const uint4*)((const unsigned short*)(wsb + WS_CP) + (size_t)b * K * 256);
#pragma unroll
    for (int jj = 0; jj < 8; jj++) {
        int j = tid + 256 * jj;  // 0..2047 uint4
        uint4 v = src[j];
        int slot = j >> 5, u = j & 31, i1 = u >> 1, half = u & 1;
        ull* d = (ull*)(slots + slot * SLOT + i1 * RS + half * 8);
        d[0] = (ull)v.x | ((ull)v.y << 32);
        d[1] = (ull)v.z | ((ull)v.w << 32);
    }
    __syncthreads();

#pragma unroll
    for (int i2 = 0; i2 < 8; i2++) {
        int i = 8 * w + i2;
        store16(slots + (64 + i) * SLOT, prod2(slots, 2 * i, 2 * i + 1, lane), lane, i & 1);
    }
#pragma unroll
    for (int i2 = 0; i2 < 4; i2++) {
        int i = 4 * w + i2;
        store16(slots + (96 + i) * SLOT, prod2(slots, 64 + 2 * i, 64 + 2 * i + 1, lane), lane, i & 1);
    }
#pragma unroll
    for (int i2 = 0; i2 < 2; i2++) {
        int i = 2 * w + i2;
        store16(slots + (112 + i) * SLOT, prod2(slots, 96 + 2 * i, 96 + 2 * i + 1, lane), lane, i & 1);
    }
    store16(slots + (120 + w) * SLOT, prod2(slots, 112 + 2 * w, 112 + 2 * w + 1, lane), lane, w & 1);
    __syncthreads();
    if (w < 2)
        store16(slots + (124 + w) * SLOT, prod2(slots, 120 + 2 * w, 120 + 2 * w + 1, lane), lane, w & 1);
    __syncthreads();
    f32x4 root = prod2(slots, 124, 125, lane);

    if (w == 0) {
        const float* initp = (const float*)(wsb + WS_INIT);
        const float* acclog = (const float*)(wsb + WS_ACC);
        float part = 0.f;
#pragma unroll
        for (int r = 0; r < 4; r++) part += initp[quad * 4 + r] * root[r];
        part += __shfl_xor(part, 16);
        part += __shfl_xor(part, 32);
        float lp = logf(part + 1e-30f) + acclog[col];
        float mx = lp;
#pragma unroll
        for (int d = 1; d < 16; d <<= 1) mx = fmaxf(mx, __shfl_xor(mx, d));
        float a2 = isfinite(mx) ? mx : 0.0f;  // jax.nn.logsumexp semantics
        float sm = expf(lp - a2);
#pragma unroll
        for (int d = 1; d < 16; d <<= 1) sm += __shfl_xor(sm, d);
        float cl = ((const float*)(wsb + WS_CLOG))[b * K + lane];
#pragma unroll
        for (int d = 1; d < 64; d <<= 1) cl += __shfl_xor(cl, d);
        if (lane == 0) out[b] = logf(sm) + a2 + cl;
    }
}

extern "C" void kernel_launch(void* const* d_in, const int* in_sizes, int n_in,
                              void* d_out, int out_size, void* d_ws, size_t ws_size,
                              hipStream_t stream) {
    const float* logx = (const float*)d_in[0];   // (B, L, C) f32
    const float* init = (const float*)d_in[1];   // (S,) f32
    const float* T    = (const float*)d_in[2];   // (S, C, S) f32
    const float* acc  = (const float*)d_in[3];   // (S,) f32
    unsigned char* wsb = (unsigned char*)d_ws;
    float* out = (float*)d_out;

    prep_kernel<<<1, 128, 0, stream>>>(init, T, acc, wsb);
    prep2_kernel<<<64, 256, 0, stream>>>(wsb);
    chunk_kernel<<<dim3(K, NB), 256, 0, stream>>>(logx, wsb);
    reduce_kernel<<<NB, 256, 0, stream>>>(wsb, out);
}